// Round 2
// baseline (8007.431 us; speedup 1.0000x reference)
//
#include <hip/hip_runtime.h>

// Koopman operator: z' = z + DT*(z@A^T + ((z@Vf)*a)@Uf), 8 steps fused.
// Storage dtype (fp32 vs bf16) detected on-device; compute is bf16 MFMA with
// fp32 master accumulators.

typedef __bf16 bf16_t;
typedef __bf16 bf16x8 __attribute__((ext_vector_type(8)));
typedef float f32x4 __attribute__((ext_vector_type(4)));

#define DT_C   0.1f
#define BMAX_C 0.3f

#define ZP 264   // z_lds row pitch (elems)
#define PP 104   // p_lds row pitch
#define AP 9     // a_lds row pitch (floats)

#define WT1_ELEMS (352 * 256)
#define WT2_ELEMS (256 * 96)

// ---------------- dtype detector --------------------------------------------
// Reads first 64 u32 of A. bf16 storage: both u16 halves of every word are
// bf16(N(0,1)*0.01) -> exponent field ~[110,123]. fp32 storage: only the high
// half looks like a bf16; low half is random mantissa bits (~13% plausible).
__global__ void detect_dtype(const unsigned int* __restrict__ Abits,
                             int* __restrict__ flag) {
  if (threadIdx.x == 0 && blockIdx.x == 0) {
    int plausible = 0;
    for (int i = 0; i < 64; ++i) {
      unsigned int w = Abits[i];
      int e0 = (int)((w >> 7) & 0xFFu);
      int e1 = (int)((w >> 23) & 0xFFu);
      plausible += (e0 >= 100 && e0 <= 133);
      plausible += (e1 >= 100 && e1 <= 133);
    }
    *flag = (plausible >= 112) ? 1 : 0;  // 1 = bf16 storage, 0 = fp32
  }
}

// ---------------- prep: fold tanh clamp + DT into transposed bf16 weights ---
// Wt1[i][j], i<256:  DT * A[i][j]
// Wt1[256+c][j]:     BMAX * tanh(B_V[l][j][r]),  c = l*16+r
// Wt2[i][c]:         DT * BMAX * tanh(B_U[l][i][r])
template <typename T, int MODE>
__global__ __launch_bounds__(256) void prep_weights(
    const int* __restrict__ flag, const T* __restrict__ A,
    const T* __restrict__ BU, const T* __restrict__ BV,
    bf16_t* __restrict__ wt1, bf16_t* __restrict__ wt2) {
  if (*flag != MODE) return;
  int idx = blockIdx.x * 256 + threadIdx.x;
  if (idx < WT1_ELEMS) {
    int i = idx >> 8;          // 0..351
    int j = idx & 255;
    float v;
    if (i < 256) {
      v = DT_C * (float)A[i * 256 + j];
    } else {
      int c = i - 256, l = c >> 4, r = c & 15;
      v = BMAX_C * tanhf((float)BV[(l * 256 + j) * 16 + r]);
    }
    wt1[idx] = (bf16_t)v;
  } else {
    int k = idx - WT1_ELEMS;
    if (k < WT2_ELEMS) {
      int i = k / 96, c = k % 96;
      int l = c >> 4, r = c & 15;
      wt2[k] = (bf16_t)(DT_C * BMAX_C * tanhf((float)BU[(l * 256 + i) * 16 + r]));
    }
  }
}

// ---------------- fused 8-step propagation ----------------------------------
// block = 256 threads = 4 waves; each wave owns 16 rows.
// z master: fp32 in MFMA C-layout regs (16 col-tiles x 4 regs), exact
// identity path. Per step: z->LDS bf16 -> A-frags (reg-stationary, K=256) ->
// GEMM1 (6 proj tiles scaled by a[row][l] + 16 A^T tiles onto z) -> proj LDS
// roundtrip -> GEMM2 (16 tiles, K=96) onto z.
template <typename T, int MODE>
__global__ __launch_bounds__(256, 2) void koopman_kernel(
    const int* __restrict__ flag, const T* __restrict__ zg,
    const T* __restrict__ ag, const int* __restrict__ steps_p,
    const bf16_t* __restrict__ wt1, const bf16_t* __restrict__ wt2,
    T* __restrict__ outg) {
  if (*flag != MODE) return;

  __shared__ __align__(16) bf16_t z_lds[64 * ZP];
  __shared__ __align__(16) bf16_t p_lds[64 * PP];
  __shared__ float a_lds[64 * AP];

  const int tid = threadIdx.x;
  const int wave = tid >> 6;
  const int lane = tid & 63;
  const int col = lane & 15;   // MFMA n / C-col
  const int quad = lane >> 4;  // MFMA lane quad
  const int wr = wave << 4;    // wave's first local row
  const long long row0 = (long long)blockIdx.x * 64;

  // ---- stage a into LDS (fp32) ----
  for (int t = tid; t < 64 * 6; t += 256) {
    int r = t / 6, l = t % 6;
    a_lds[r * AP + l] = (float)ag[(row0 + r) * 6 + l];
  }

  // ---- z master into C-layout fp32 regs, straight from global (exact) ----
  f32x4 zacc[16];
#pragma unroll
  for (int ct = 0; ct < 16; ++ct) {
#pragma unroll
    for (int reg = 0; reg < 4; ++reg)
      zacc[ct][reg] =
          (float)zg[(row0 + wr + quad * 4 + reg) * 256 + ct * 16 + col];
  }

  const int steps = steps_p[0];

  for (int s = 0; s < steps; ++s) {
    // write current z (bf16) into this wave's LDS rows (C-layout scatter)
#pragma unroll
    for (int ct = 0; ct < 16; ++ct) {
#pragma unroll
      for (int reg = 0; reg < 4; ++reg)
        z_lds[(wr + quad * 4 + reg) * ZP + ct * 16 + col] =
            (bf16_t)zacc[ct][reg];
    }
    __syncthreads();

    // A-frags for this wave's 16 rows, all K=256 (8 frags, reg-stationary)
    bf16x8 zf[8];
#pragma unroll
    for (int kk = 0; kk < 8; ++kk)
      zf[kk] = *(const bf16x8*)&z_lds[(wr + col) * ZP + kk * 32 + quad * 8];

    // ---- phase 1a: proj tiles (cols 256..351 of Wt1), scale by a, to LDS --
#pragma unroll
    for (int l = 0; l < 6; ++l) {
      f32x4 acc = {0.f, 0.f, 0.f, 0.f};
#pragma unroll
      for (int kk = 0; kk < 8; ++kk) {
        bf16x8 bfrag = *(const bf16x8*)&wt1[(size_t)(256 + l * 16 + col) * 256 +
                                            kk * 32 + quad * 8];
        acc = __builtin_amdgcn_mfma_f32_16x16x32_bf16(zf[kk], bfrag, acc, 0, 0, 0);
      }
#pragma unroll
      for (int reg = 0; reg < 4; ++reg) {
        float sc = a_lds[(wr + quad * 4 + reg) * AP + l];
        p_lds[(wr + quad * 4 + reg) * PP + l * 16 + col] =
            (bf16_t)(acc[reg] * sc);
      }
    }

    // ---- phase 1b: z += z @ (DT*A^T) --------------------------------------
#pragma unroll
    for (int ct = 0; ct < 16; ++ct) {
      f32x4 acc = zacc[ct];
#pragma unroll
      for (int kk = 0; kk < 8; ++kk) {
        bf16x8 bfrag = *(const bf16x8*)&wt1[(size_t)(ct * 16 + col) * 256 +
                                            kk * 32 + quad * 8];
        acc = __builtin_amdgcn_mfma_f32_16x16x32_bf16(zf[kk], bfrag, acc, 0, 0, 0);
      }
      zacc[ct] = acc;
    }
    __syncthreads();

    // ---- phase 2: z += (proj*a) @ (DT*Uf), K=96 ---------------------------
    bf16x8 pf[3];
#pragma unroll
    for (int kk = 0; kk < 3; ++kk)
      pf[kk] = *(const bf16x8*)&p_lds[(wr + col) * PP + kk * 32 + quad * 8];
#pragma unroll
    for (int ct = 0; ct < 16; ++ct) {
      f32x4 acc = zacc[ct];
#pragma unroll
      for (int kk = 0; kk < 3; ++kk) {
        bf16x8 bfrag = *(const bf16x8*)&wt2[(size_t)(ct * 16 + col) * 96 +
                                            kk * 32 + quad * 8];
        acc = __builtin_amdgcn_mfma_f32_16x16x32_bf16(pf[kk], bfrag, acc, 0, 0, 0);
      }
      zacc[ct] = acc;
    }
    __syncthreads();
  }

  // ---- epilogue: direct C-layout stores in native dtype (exact for fp32) --
#pragma unroll
  for (int ct = 0; ct < 16; ++ct) {
#pragma unroll
    for (int reg = 0; reg < 4; ++reg)
      outg[(row0 + wr + quad * 4 + reg) * 256 + ct * 16 + col] =
          (T)zacc[ct][reg];
  }
}

extern "C" void kernel_launch(void* const* d_in, const int* in_sizes, int n_in,
                              void* d_out, int out_size, void* d_ws,
                              size_t ws_size, hipStream_t stream) {
  const void* z = d_in[0];
  const void* a = d_in[1];
  const void* A = d_in[2];
  const void* BU = d_in[3];
  const void* BV = d_in[4];
  const int* steps = (const int*)d_in[5];

  int* flag = (int*)d_ws;
  bf16_t* wt1 = (bf16_t*)((char*)d_ws + 16);
  bf16_t* wt2 = wt1 + WT1_ELEMS;

  const int N = in_sizes[0] / 256;  // 262144 rows

  detect_dtype<<<1, 64, 0, stream>>>((const unsigned int*)A, flag);

  // 352*256 + 256*96 = 114688 elements == 448 * 256 threads
  prep_weights<float, 0><<<448, 256, 0, stream>>>(
      flag, (const float*)A, (const float*)BU, (const float*)BV, wt1, wt2);
  prep_weights<bf16_t, 1><<<448, 256, 0, stream>>>(
      flag, (const bf16_t*)A, (const bf16_t*)BU, (const bf16_t*)BV, wt1, wt2);

  koopman_kernel<float, 0><<<N / 64, 256, 0, stream>>>(
      flag, (const float*)z, (const float*)a, steps, wt1, wt2, (float*)d_out);
  koopman_kernel<bf16_t, 1><<<N / 64, 256, 0, stream>>>(
      flag, (const bf16_t*)z, (const bf16_t*)a, steps, wt1, wt2,
      (bf16_t*)d_out);
}